// Round 3
// baseline (692.069 us; speedup 1.0000x reference)
//
#include <hip/hip_runtime.h>
#include <math.h>

#define BB 4
#define CC 256
#define NN 4096

using half8 = __attribute__((ext_vector_type(8))) _Float16;
using f32x4 = __attribute__((ext_vector_type(4))) float;

__device__ __forceinline__ unsigned short f2h(float f) {
  _Float16 h = (_Float16)f;   // RNE
  return __builtin_bit_cast(unsigned short, h);
}

// ---------------- transpose: x (B,C,N) f32 -> Xt (B,N,C) fp16 ----------------
__global__ __launch_bounds__(256) void k_transpose(const float* __restrict__ x,
                                                   unsigned short* __restrict__ Xt) {
  __shared__ float tile[64][65];
  int b = blockIdx.z, c0 = blockIdx.y * 64, n0 = blockIdx.x * 64;
  int t = threadIdx.x;
  const float* xp = x + ((size_t)b * CC + c0) * NN + n0;
#pragma unroll
  for (int p = 0; p < 4; ++p) {
    int c = p * 16 + (t >> 4);
    int j = (t & 15) * 4;
    float4 v = *(const float4*)(xp + (size_t)c * NN + j);
    tile[c][j] = v.x; tile[c][j + 1] = v.y; tile[c][j + 2] = v.z; tile[c][j + 3] = v.w;
  }
  __syncthreads();
  unsigned short* xtp = Xt + ((size_t)b * NN + n0) * CC + c0;
#pragma unroll
  for (int p = 0; p < 2; ++p) {
    int n = p * 32 + (t >> 3);
    int cb = (t & 7) * 8;
    union { unsigned short u[8]; uint4 v; } tmp;
#pragma unroll
    for (int i = 0; i < 8; ++i) tmp.u[i] = f2h(tile[cb + i][n]);
    *(uint4*)(xtp + (size_t)n * CC + cb) = tmp.v;
  }
}

// ---------------- projections ----------------
// Q[b,n,o] = sum_c Xt[b,n,c]*Wq[o,c] + bq[o]   stored (B,N,C) fp16
// K same with Wk; V same product with Wv but stored transposed (B,C,N) fp16.
__global__ __launch_bounds__(256, 1) void k_proj(const unsigned short* __restrict__ Xt,
    const float* __restrict__ Wq, const float* __restrict__ bq,
    const float* __restrict__ Wk, const float* __restrict__ bk,
    const float* __restrict__ Wv, const float* __restrict__ bv,
    unsigned short* __restrict__ Q, unsigned short* __restrict__ K,
    unsigned short* __restrict__ V) {
  __shared__ union {
    struct { unsigned short xa[128][72]; unsigned short wb[256][72]; } s;
    unsigned short qo[128][264];
    unsigned short vo[256][136];
  } u;
  int proj = blockIdx.z;
  const float* W    = proj == 0 ? Wq : (proj == 1 ? Wk : Wv);
  const float* bias = proj == 0 ? bq : (proj == 1 ? bk : bv);
  int b = blockIdx.y, n0 = blockIdx.x * 128;
  int t = threadIdx.x, w = t >> 6, lane = t & 63, l15 = lane & 15, quad = lane >> 4;

  f32x4 z = {0.f, 0.f, 0.f, 0.f};
  f32x4 acc[2][16];
#pragma unroll
  for (int i = 0; i < 2; ++i)
#pragma unroll
    for (int j = 0; j < 16; ++j) acc[i][j] = z;

  for (int ks = 0; ks < 4; ++ks) {   // K loop, BK=64
    __syncthreads();
#pragma unroll
    for (int p = 0; p < 4; ++p) {    // stage Xt 128x64 fp16
      int r = p * 32 + (t >> 3);
      *(uint4*)&u.s.xa[r][(t & 7) * 8] =
        *(const uint4*)(Xt + ((size_t)b * NN + n0 + r) * CC + ks * 64 + (t & 7) * 8);
    }
#pragma unroll
    for (int p = 0; p < 16; ++p) {   // stage W 256x64 f32->fp16
      int r = p * 16 + (t >> 4);
      float4 wv = *(const float4*)(W + (size_t)r * CC + ks * 64 + (t & 15) * 4);
      ushort4 pk;
      pk.x = f2h(wv.x); pk.y = f2h(wv.y); pk.z = f2h(wv.z); pk.w = f2h(wv.w);
      *(ushort4*)&u.s.wb[r][(t & 15) * 4] = pk;
    }
    __syncthreads();
#pragma unroll
    for (int kc = 0; kc < 2; ++kc) {
      half8 af[2];
#pragma unroll
      for (int nt = 0; nt < 2; ++nt)
        af[nt] = *(const half8*)&u.s.xa[w * 32 + nt * 16 + l15][kc * 32 + quad * 8];
#pragma unroll
      for (int ct = 0; ct < 16; ++ct) {
        half8 bf = *(const half8*)&u.s.wb[ct * 16 + l15][kc * 32 + quad * 8];
        acc[0][ct] = __builtin_amdgcn_mfma_f32_16x16x32_f16(af[0], bf, acc[0][ct], 0, 0, 0);
        acc[1][ct] = __builtin_amdgcn_mfma_f32_16x16x32_f16(af[1], bf, acc[1][ct], 0, 0, 0);
      }
    }
  }
#pragma unroll
  for (int ct = 0; ct < 16; ++ct) {
    float bv_ = bias[ct * 16 + l15];
#pragma unroll
    for (int nt = 0; nt < 2; ++nt)
#pragma unroll
      for (int r = 0; r < 4; ++r) acc[nt][ct][r] += bv_;
  }
  __syncthreads();
  if (proj < 2) {
#pragma unroll
    for (int nt = 0; nt < 2; ++nt)
#pragma unroll
      for (int ct = 0; ct < 16; ++ct)
#pragma unroll
        for (int r = 0; r < 4; ++r)
          u.qo[w * 32 + nt * 16 + quad * 4 + r][ct * 16 + l15] = f2h(acc[nt][ct][r]);
    __syncthreads();
    unsigned short* out = (proj == 0 ? Q : K) + ((size_t)b * NN + n0) * CC;
#pragma unroll
    for (int p = 0; p < 16; ++p) {
      int f = p * 4096 + t * 16;
      int n = f >> 9, ob = f & 511;
      *(uint4*)((char*)out + (size_t)n * 512 + ob) =
        *(const uint4*)((const char*)&u.qo[n][0] + ob);
    }
  } else {
#pragma unroll
    for (int nt = 0; nt < 2; ++nt)
#pragma unroll
      for (int ct = 0; ct < 16; ++ct)
#pragma unroll
        for (int r = 0; r < 4; ++r)
          u.vo[ct * 16 + l15][w * 32 + nt * 16 + quad * 4 + r] = f2h(acc[nt][ct][r]);
    __syncthreads();
    unsigned short* out = V + (size_t)b * CC * NN + n0;
    // 256 rows x 128 cols (256 B/row); 256 threads x 16 B = 16 rows/pass -> 16 passes
#pragma unroll
    for (int p = 0; p < 16; ++p) {
      int o = p * 16 + (t >> 4);
      *(uint4*)((char*)out + (size_t)o * NN * 2 + (t & 15) * 16) =
        *(const uint4*)&u.vo[o][(t & 15) * 8];
    }
  }
}

// ---------------- flash attention ----------------
// out[b,c,n] = sum_m softmax_m(Q[n,:].K[m,:]) * V[c,m]
__global__ __launch_bounds__(256, 1) void k_flash(const unsigned short* __restrict__ Q,
    const unsigned short* __restrict__ K, const unsigned short* __restrict__ V,
    float* __restrict__ out) {
  __shared__ union {
    struct {
      unsigned short kt[64][264];   // K tile: 64 keys x 256 c
      unsigned short vt[256][72];   // V tile: 256 c x 64 keys
      unsigned short pt[4][16][72]; // per-wave P scratch: 16 q x 64 keys
    } s;
    float od[256][68];              // epilogue: [c][q]
  } u;
  int b = blockIdx.y, q0 = blockIdx.x * 64;
  int t = threadIdx.x, w = t >> 6, lane = t & 63, l15 = lane & 15, quad = lane >> 4;

  // Q fragments in registers (loop-invariant): A[q=l15][c=quad*8+j]
  half8 qf[8];
  const unsigned short* qrow = Q + ((size_t)b * NN + q0 + w * 16 + l15) * CC;
#pragma unroll
  for (int k = 0; k < 8; ++k) qf[k] = *(const half8*)(qrow + k * 32 + quad * 8);

  f32x4 z = {0.f, 0.f, 0.f, 0.f};
  f32x4 o_acc[16];
#pragma unroll
  for (int i = 0; i < 16; ++i) o_acc[i] = z;
  float m_i[4], l_i[4];
#pragma unroll
  for (int r = 0; r < 4; ++r) { m_i[r] = -INFINITY; l_i[r] = 0.f; }

  for (int kt = 0; kt < 64; ++kt) {
    __syncthreads();
    const unsigned short* kbase = K + ((size_t)b * NN + kt * 64) * CC;
#pragma unroll
    for (int p = 0; p < 8; ++p) {   // K tile: 32 KB contiguous
      int f = p * 4096 + t * 16;
      int r = f >> 9, ob = f & 511;
      *(uint4*)((char*)&u.s.kt[r][0] + ob) = *(const uint4*)((const char*)kbase + f);
    }
    const unsigned short* vbase = V + (size_t)b * CC * NN + kt * 64;
#pragma unroll
    for (int p = 0; p < 8; ++p) {   // V tile: 256 rows x 128 B
      int c = p * 32 + (t >> 3);
      *(uint4*)&u.s.vt[c][(t & 7) * 8] = *(const uint4*)(vbase + (size_t)c * NN + (t & 7) * 8);
    }
    __syncthreads();

    // S = Q K^T : 16 q x 64 keys per wave
    f32x4 sa[4];
#pragma unroll
    for (int j = 0; j < 4; ++j) sa[j] = z;
#pragma unroll
    for (int k = 0; k < 8; ++k) {
#pragma unroll
      for (int j = 0; j < 4; ++j) {
        half8 bf = *(const half8*)&u.s.kt[j * 16 + l15][k * 32 + quad * 8];
        sa[j] = __builtin_amdgcn_mfma_f32_16x16x32_f16(qf[k], bf, sa[j], 0, 0, 0);
      }
    }
    // online softmax; row = quad*4 + r, cols spread over 16 lanes of the quad
    float mt[4];
#pragma unroll
    for (int r = 0; r < 4; ++r)
      mt[r] = fmaxf(fmaxf(sa[0][r], sa[1][r]), fmaxf(sa[2][r], sa[3][r]));
#pragma unroll
    for (int off = 1; off < 16; off <<= 1)
#pragma unroll
      for (int r = 0; r < 4; ++r)
        mt[r] = fmaxf(mt[r], __shfl_xor(mt[r], off, 64));
    float alpha[4], rs[4];
#pragma unroll
    for (int r = 0; r < 4; ++r) {
      float mn = fmaxf(m_i[r], mt[r]);
      alpha[r] = __expf(m_i[r] - mn);
      m_i[r] = mn;
      rs[r] = 0.f;
    }
#pragma unroll
    for (int j = 0; j < 4; ++j)
#pragma unroll
      for (int r = 0; r < 4; ++r) {
        float p = __expf(sa[j][r] - m_i[r]);
        sa[j][r] = p;
        rs[r] += p;
      }
#pragma unroll
    for (int off = 1; off < 16; off <<= 1)
#pragma unroll
      for (int r = 0; r < 4; ++r)
        rs[r] += __shfl_xor(rs[r], off, 64);
#pragma unroll
    for (int r = 0; r < 4; ++r) l_i[r] = l_i[r] * alpha[r] + rs[r];
#pragma unroll
    for (int ct = 0; ct < 16; ++ct)
#pragma unroll
      for (int r = 0; r < 4; ++r) o_acc[ct][r] *= alpha[r];
    // P (C/D layout) -> LDS -> A-operand layout (within-wave, no barrier needed)
#pragma unroll
    for (int j = 0; j < 4; ++j)
#pragma unroll
      for (int r = 0; r < 4; ++r)
        u.s.pt[w][quad * 4 + r][j * 16 + l15] = f2h(sa[j][r]);
    // O += P @ V^T
#pragma unroll
    for (int mc = 0; mc < 2; ++mc) {
      half8 af = *(const half8*)&u.s.pt[w][l15][mc * 32 + quad * 8];
#pragma unroll
      for (int ct = 0; ct < 16; ++ct) {
        half8 bf = *(const half8*)&u.s.vt[ct * 16 + l15][mc * 32 + quad * 8];
        o_acc[ct] = __builtin_amdgcn_mfma_f32_16x16x32_f16(af, bf, o_acc[ct], 0, 0, 0);
      }
    }
  }
  float inv[4];
#pragma unroll
  for (int r = 0; r < 4; ++r) inv[r] = 1.f / l_i[r];
  __syncthreads();
#pragma unroll
  for (int ct = 0; ct < 16; ++ct)
#pragma unroll
    for (int r = 0; r < 4; ++r)
      u.od[ct * 16 + l15][w * 16 + quad * 4 + r] = o_acc[ct][r] * inv[r];
  __syncthreads();
  float* ob = out + (size_t)b * CC * NN + q0;
#pragma unroll
  for (int p = 0; p < 16; ++p) {
    int c = p * 16 + (t >> 4);
    *(float4*)(ob + (size_t)c * NN + (t & 15) * 4) = *(const float4*)&u.od[c][(t & 15) * 4];
  }
}

extern "C" void kernel_launch(void* const* d_in, const int* in_sizes, int n_in,
                              void* d_out, int out_size, void* d_ws, size_t ws_size,
                              hipStream_t stream) {
  const float* x  = (const float*)d_in[0];
  const float* Wq = (const float*)d_in[1];
  const float* bq = (const float*)d_in[2];
  const float* Wk = (const float*)d_in[3];
  const float* bk = (const float*)d_in[4];
  const float* Wv = (const float*)d_in[5];
  const float* bv = (const float*)d_in[6];
  float* out = (float*)d_out;
  char* ws = (char*)d_ws;
  // 4 buffers of exactly 8 MiB each: Xt, Q, K (B,N,C) / V (B,C,N), all fp16
  unsigned short* Xt = (unsigned short*)(ws);
  unsigned short* Qb = (unsigned short*)(ws + (size_t)8  * 1024 * 1024);
  unsigned short* Kb = (unsigned short*)(ws + (size_t)16 * 1024 * 1024);
  unsigned short* Vb = (unsigned short*)(ws + (size_t)24 * 1024 * 1024);

  k_transpose<<<dim3(64, 4, 4), 256, 0, stream>>>(x, Xt);
  k_proj<<<dim3(32, 4, 3), 256, 0, stream>>>(Xt, Wq, bq, Wk, bk, Wv, bv, Qb, Kb, Vb);
  k_flash<<<dim3(64, 4), 256, 0, stream>>>(Qb, Kb, Vb, out);
}

// Round 4
// 590.047 us; speedup vs baseline: 1.1729x; 1.1729x over previous
//
#include <hip/hip_runtime.h>
#include <math.h>

#define BB 4
#define CC 256
#define NN 4096

using half8 = __attribute__((ext_vector_type(8))) _Float16;
using f32x4 = __attribute__((ext_vector_type(4))) float;

__device__ __forceinline__ unsigned short f2h(float f) {
  _Float16 h = (_Float16)f;   // RNE
  return __builtin_bit_cast(unsigned short, h);
}

// XOR bank swizzle: 16B chunks within a row permuted by row&7 so that
// fragment reads (16 rows x 16B) spread over all 32 banks (<=2-way = free).
__device__ __forceinline__ int kt_off(int r, int chunk) {   // kt: 64 rows x 512B, shorts
  return r * 256 + (((chunk & 24) | ((chunk ^ r) & 7)) << 3);
}
__device__ __forceinline__ int vt_off(int r, int chunk) {   // vt: 256 rows x 128B, shorts
  return r * 64 + (((chunk ^ r) & 7) << 3);
}

// ---------------- transpose: x (B,C,N) f32 -> Xt (B,N,C) fp16 ----------------
__global__ __launch_bounds__(256) void k_transpose(const float* __restrict__ x,
                                                   unsigned short* __restrict__ Xt) {
  __shared__ float tile[64][65];
  int b = blockIdx.z, c0 = blockIdx.y * 64, n0 = blockIdx.x * 64;
  int t = threadIdx.x;
  const float* xp = x + ((size_t)b * CC + c0) * NN + n0;
#pragma unroll
  for (int p = 0; p < 4; ++p) {
    int c = p * 16 + (t >> 4);
    int j = (t & 15) * 4;
    float4 v = *(const float4*)(xp + (size_t)c * NN + j);
    tile[c][j] = v.x; tile[c][j + 1] = v.y; tile[c][j + 2] = v.z; tile[c][j + 3] = v.w;
  }
  __syncthreads();
  unsigned short* xtp = Xt + ((size_t)b * NN + n0) * CC + c0;
#pragma unroll
  for (int p = 0; p < 2; ++p) {
    int n = p * 32 + (t >> 3);
    int cb = (t & 7) * 8;
    union { unsigned short u[8]; uint4 v; } tmp;
#pragma unroll
    for (int i = 0; i < 8; ++i) tmp.u[i] = f2h(tile[cb + i][n]);
    *(uint4*)(xtp + (size_t)n * CC + cb) = tmp.v;
  }
}

// ---------------- projections ----------------
__global__ __launch_bounds__(256, 1) void k_proj(const unsigned short* __restrict__ Xt,
    const float* __restrict__ Wq, const float* __restrict__ bq,
    const float* __restrict__ Wk, const float* __restrict__ bk,
    const float* __restrict__ Wv, const float* __restrict__ bv,
    unsigned short* __restrict__ Q, unsigned short* __restrict__ K,
    unsigned short* __restrict__ V) {
  __shared__ union {
    struct { unsigned short xa[128][72]; unsigned short wb[256][72]; } s;
    unsigned short qo[128][264];
    unsigned short vo[256][136];
  } u;
  int proj = blockIdx.z;
  const float* W    = proj == 0 ? Wq : (proj == 1 ? Wk : Wv);
  const float* bias = proj == 0 ? bq : (proj == 1 ? bk : bv);
  int b = blockIdx.y, n0 = blockIdx.x * 128;
  int t = threadIdx.x, w = t >> 6, lane = t & 63, l15 = lane & 15, quad = lane >> 4;

  f32x4 z = {0.f, 0.f, 0.f, 0.f};
  f32x4 acc[2][16];
#pragma unroll
  for (int i = 0; i < 2; ++i)
#pragma unroll
    for (int j = 0; j < 16; ++j) acc[i][j] = z;

  for (int ks = 0; ks < 4; ++ks) {
    __syncthreads();
#pragma unroll
    for (int p = 0; p < 4; ++p) {
      int r = p * 32 + (t >> 3);
      *(uint4*)&u.s.xa[r][(t & 7) * 8] =
        *(const uint4*)(Xt + ((size_t)b * NN + n0 + r) * CC + ks * 64 + (t & 7) * 8);
    }
#pragma unroll
    for (int p = 0; p < 16; ++p) {
      int r = p * 16 + (t >> 4);
      float4 wv = *(const float4*)(W + (size_t)r * CC + ks * 64 + (t & 15) * 4);
      ushort4 pk;
      pk.x = f2h(wv.x); pk.y = f2h(wv.y); pk.z = f2h(wv.z); pk.w = f2h(wv.w);
      *(ushort4*)&u.s.wb[r][(t & 15) * 4] = pk;
    }
    __syncthreads();
#pragma unroll
    for (int kc = 0; kc < 2; ++kc) {
      half8 af[2];
#pragma unroll
      for (int nt = 0; nt < 2; ++nt)
        af[nt] = *(const half8*)&u.s.xa[w * 32 + nt * 16 + l15][kc * 32 + quad * 8];
#pragma unroll
      for (int ct = 0; ct < 16; ++ct) {
        half8 bf = *(const half8*)&u.s.wb[ct * 16 + l15][kc * 32 + quad * 8];
        acc[0][ct] = __builtin_amdgcn_mfma_f32_16x16x32_f16(af[0], bf, acc[0][ct], 0, 0, 0);
        acc[1][ct] = __builtin_amdgcn_mfma_f32_16x16x32_f16(af[1], bf, acc[1][ct], 0, 0, 0);
      }
    }
  }
#pragma unroll
  for (int ct = 0; ct < 16; ++ct) {
    float bv_ = bias[ct * 16 + l15];
#pragma unroll
    for (int nt = 0; nt < 2; ++nt)
#pragma unroll
      for (int r = 0; r < 4; ++r) acc[nt][ct][r] += bv_;
  }
  __syncthreads();
  if (proj < 2) {
#pragma unroll
    for (int nt = 0; nt < 2; ++nt)
#pragma unroll
      for (int ct = 0; ct < 16; ++ct)
#pragma unroll
        for (int r = 0; r < 4; ++r)
          u.qo[w * 32 + nt * 16 + quad * 4 + r][ct * 16 + l15] = f2h(acc[nt][ct][r]);
    __syncthreads();
    unsigned short* out = (proj == 0 ? Q : K) + ((size_t)b * NN + n0) * CC;
#pragma unroll
    for (int p = 0; p < 16; ++p) {
      int f = p * 4096 + t * 16;
      int n = f >> 9, ob = f & 511;
      *(uint4*)((char*)out + (size_t)n * 512 + ob) =
        *(const uint4*)((const char*)&u.qo[n][0] + ob);
    }
  } else {
#pragma unroll
    for (int nt = 0; nt < 2; ++nt)
#pragma unroll
      for (int ct = 0; ct < 16; ++ct)
#pragma unroll
        for (int r = 0; r < 4; ++r)
          u.vo[ct * 16 + l15][w * 32 + nt * 16 + quad * 4 + r] = f2h(acc[nt][ct][r]);
    __syncthreads();
    unsigned short* out = V + (size_t)b * CC * NN + n0;
#pragma unroll
    for (int p = 0; p < 16; ++p) {
      int o = p * 16 + (t >> 4);
      *(uint4*)((char*)out + (size_t)o * NN * 2 + (t & 15) * 16) =
        *(const uint4*)&u.vo[o][(t & 15) * 8];
    }
  }
}

// ---------------- flash attention (key-split) ----------------
// out[b,c,n] = sum_m softmax_m(Q[n,:].K[m,:]) * V[c,m]
__global__ __launch_bounds__(256, 1) void k_flash(const unsigned short* __restrict__ Q,
    const unsigned short* __restrict__ K, const unsigned short* __restrict__ V,
    float* __restrict__ out, float* __restrict__ opart, float* __restrict__ ml,
    int n_splits) {
  __shared__ union {
    struct {
      unsigned short kt[64 * 256];  // 64 keys x 256 c (swizzled)
      unsigned short vt[256 * 64];  // 256 c x 64 keys (swizzled)
      unsigned short pt[4 * 16 * 64]; // per-wave P scratch (swizzled)
    } s;
    float od[256][68];
  } u;
  int b = blockIdx.y, q0 = blockIdx.x * 64, split = blockIdx.z;
  int nper = 64 / n_splits;
  int t = threadIdx.x, w = t >> 6, lane = t & 63, l15 = lane & 15, quad = lane >> 4;

  half8 qf[8];
  const unsigned short* qrow = Q + ((size_t)b * NN + q0 + w * 16 + l15) * CC;
#pragma unroll
  for (int k = 0; k < 8; ++k) qf[k] = *(const half8*)(qrow + k * 32 + quad * 8);

  f32x4 z = {0.f, 0.f, 0.f, 0.f};
  f32x4 o_acc[16];
#pragma unroll
  for (int i = 0; i < 16; ++i) o_acc[i] = z;
  float m_i[4], l_i[4];
#pragma unroll
  for (int r = 0; r < 4; ++r) { m_i[r] = -INFINITY; l_i[r] = 0.f; }

  for (int it = split * nper; it < split * nper + nper; ++it) {
    __syncthreads();
    const unsigned short* kbase = K + ((size_t)b * NN + it * 64) * CC;
#pragma unroll
    for (int p = 0; p < 8; ++p) {
      int f = p * 4096 + t * 16;           // bytes in 32KB tile
      int r = f >> 9, chunk = (f >> 4) & 31;
      *(uint4*)&u.s.kt[kt_off(r, chunk)] = *(const uint4*)((const char*)kbase + f);
    }
    const unsigned short* vbase = V + (size_t)b * CC * NN + it * 64;
#pragma unroll
    for (int p = 0; p < 8; ++p) {
      int c = p * 32 + (t >> 3);
      *(uint4*)&u.s.vt[vt_off(c, t & 7)] = *(const uint4*)(vbase + (size_t)c * NN + (t & 7) * 8);
    }
    __syncthreads();

    // S = Q K^T : 16 q x 64 keys per wave
    f32x4 sa[4];
#pragma unroll
    for (int j = 0; j < 4; ++j) sa[j] = z;
#pragma unroll
    for (int k = 0; k < 8; ++k) {
#pragma unroll
      for (int j = 0; j < 4; ++j) {
        half8 bf = *(const half8*)&u.s.kt[kt_off(j * 16 + l15, 4 * k + quad)];
        sa[j] = __builtin_amdgcn_mfma_f32_16x16x32_f16(qf[k], bf, sa[j], 0, 0, 0);
      }
    }
    // online softmax
    float mt[4];
#pragma unroll
    for (int r = 0; r < 4; ++r)
      mt[r] = fmaxf(fmaxf(sa[0][r], sa[1][r]), fmaxf(sa[2][r], sa[3][r]));
#pragma unroll
    for (int off = 1; off < 16; off <<= 1)
#pragma unroll
      for (int r = 0; r < 4; ++r)
        mt[r] = fmaxf(mt[r], __shfl_xor(mt[r], off, 64));
    float alpha[4], rs[4];
#pragma unroll
    for (int r = 0; r < 4; ++r) {
      float mn = fmaxf(m_i[r], mt[r]);
      alpha[r] = __expf(m_i[r] - mn);
      m_i[r] = mn;
      rs[r] = 0.f;
    }
#pragma unroll
    for (int j = 0; j < 4; ++j)
#pragma unroll
      for (int r = 0; r < 4; ++r) {
        float p = __expf(sa[j][r] - m_i[r]);
        sa[j][r] = p;
        rs[r] += p;
      }
#pragma unroll
    for (int off = 1; off < 16; off <<= 1)
#pragma unroll
      for (int r = 0; r < 4; ++r)
        rs[r] += __shfl_xor(rs[r], off, 64);
#pragma unroll
    for (int r = 0; r < 4; ++r) l_i[r] = l_i[r] * alpha[r] + rs[r];
#pragma unroll
    for (int ct = 0; ct < 16; ++ct)
#pragma unroll
      for (int r = 0; r < 4; ++r) o_acc[ct][r] *= alpha[r];
    // P (C/D layout) -> LDS -> A-operand layout (within-wave)
#pragma unroll
    for (int j = 0; j < 4; ++j)
#pragma unroll
      for (int r = 0; r < 4; ++r) {
        int row = quad * 4 + r;
        int chunk = 2 * j + (l15 >> 3);
        u.s.pt[w * 1024 + row * 64 + (((chunk ^ row) & 7) << 3) + (l15 & 7)] = f2h(sa[j][r]);
      }
    // O += P @ V^T
#pragma unroll
    for (int mc = 0; mc < 2; ++mc) {
      half8 af = *(const half8*)&u.s.pt[w * 1024 + l15 * 64 + ((((mc * 4 + quad) ^ l15) & 7) << 3)];
#pragma unroll
      for (int ct = 0; ct < 16; ++ct) {
        half8 bf = *(const half8*)&u.s.vt[vt_off(ct * 16 + l15, mc * 4 + quad)];
        o_acc[ct] = __builtin_amdgcn_mfma_f32_16x16x32_f16(af, bf, o_acc[ct], 0, 0, 0);
      }
    }
  }
  float sc[4];
#pragma unroll
  for (int r = 0; r < 4; ++r) sc[r] = (n_splits == 1) ? 1.f / l_i[r] : 1.f;
  __syncthreads();
#pragma unroll
  for (int ct = 0; ct < 16; ++ct)
#pragma unroll
    for (int r = 0; r < 4; ++r)
      u.od[ct * 16 + l15][w * 16 + quad * 4 + r] = o_acc[ct][r] * sc[r];
  __syncthreads();
  float* ob = (n_splits == 1 ? out : opart + (size_t)split * BB * CC * NN)
              + (size_t)b * CC * NN + q0;
#pragma unroll
  for (int p = 0; p < 16; ++p) {
    int c = p * 16 + (t >> 4);
    *(float4*)(ob + (size_t)c * NN + (t & 15) * 4) = *(const float4*)&u.od[c][(t & 15) * 4];
  }
  if (n_splits != 1 && l15 == 0) {
    float* mp = ml + ((size_t)(split * 2 + 0) * BB + b) * NN + q0 + w * 16 + quad * 4;
    float* lp = ml + ((size_t)(split * 2 + 1) * BB + b) * NN + q0 + w * 16 + quad * 4;
#pragma unroll
    for (int r = 0; r < 4; ++r) { mp[r] = m_i[r]; lp[r] = l_i[r]; }
  }
}

// ---------------- merge of 2 key-splits ----------------
__global__ __launch_bounds__(256) void k_merge(const float* __restrict__ opart,
    const float* __restrict__ ml, float* __restrict__ out) {
  size_t i = ((size_t)blockIdx.x * 256 + threadIdx.x) * 4;
  int n = (int)(i & (NN - 1));
  int b = (int)(i >> 20);   // i / (CC*NN)
  float4 m1 = *(const float4*)(ml + (size_t)(0 * BB + b) * NN + n);
  float4 l1 = *(const float4*)(ml + (size_t)(1 * BB + b) * NN + n);
  float4 m2 = *(const float4*)(ml + (size_t)(2 * BB + b) * NN + n);
  float4 l2 = *(const float4*)(ml + (size_t)(3 * BB + b) * NN + n);
  float4 o1 = *(const float4*)(opart + i);
  float4 o2 = *(const float4*)(opart + (size_t)BB * CC * NN + i);
  float4 o;
#define MERGE1(f) { \
    float mm = fmaxf(m1.f, m2.f); \
    float e1 = __expf(m1.f - mm), e2 = __expf(m2.f - mm); \
    o.f = (e1 * o1.f + e2 * o2.f) / (e1 * l1.f + e2 * l2.f); }
  MERGE1(x) MERGE1(y) MERGE1(z) MERGE1(w)
#undef MERGE1
  *(float4*)(out + i) = o;
}

extern "C" void kernel_launch(void* const* d_in, const int* in_sizes, int n_in,
                              void* d_out, int out_size, void* d_ws, size_t ws_size,
                              hipStream_t stream) {
  const float* x  = (const float*)d_in[0];
  const float* Wq = (const float*)d_in[1];
  const float* bq = (const float*)d_in[2];
  const float* Wk = (const float*)d_in[3];
  const float* bk = (const float*)d_in[4];
  const float* Wv = (const float*)d_in[5];
  const float* bv = (const float*)d_in[6];
  float* out = (float*)d_out;
  char* ws = (char*)d_ws;
  unsigned short* Xt = (unsigned short*)(ws);
  unsigned short* Qb = (unsigned short*)(ws + (size_t)8  * 1024 * 1024);
  unsigned short* Kb = (unsigned short*)(ws + (size_t)16 * 1024 * 1024);
  unsigned short* Vb = (unsigned short*)(ws + (size_t)24 * 1024 * 1024);
  float* Opart = (float*)(ws + (size_t)32 * 1024 * 1024);  // 2 x 16 MB
  float* Ml    = (float*)(ws + (size_t)64 * 1024 * 1024);  // 4 x 64 KB

  k_transpose<<<dim3(64, 4, 4), 256, 0, stream>>>(x, Xt);
  k_proj<<<dim3(32, 4, 3), 256, 0, stream>>>(Xt, Wq, bq, Wk, bk, Wv, bv, Qb, Kb, Vb);

  bool split2 = ws_size >= (size_t)68 * 1024 * 1024;
  if (split2) {
    k_flash<<<dim3(64, 4, 2), 256, 0, stream>>>(Qb, Kb, Vb, out, Opart, Ml, 2);
    k_merge<<<dim3(4096), 256, 0, stream>>>(Opart, Ml, out);
  } else {
    k_flash<<<dim3(64, 4, 1), 256, 0, stream>>>(Qb, Kb, Vb, out, Opart, Ml, 1);
  }
}

// Round 5
// 525.800 us; speedup vs baseline: 1.3162x; 1.1222x over previous
//
#include <hip/hip_runtime.h>
#include <math.h>

#define BB 4
#define CC 256
#define NN 4096

using half8 = __attribute__((ext_vector_type(8))) _Float16;
using f32x4 = __attribute__((ext_vector_type(4))) float;

__device__ __forceinline__ unsigned short f2h(float f) {
  _Float16 h = (_Float16)f;   // RNE
  return __builtin_bit_cast(unsigned short, h);
}

// XOR bank swizzle at 16B-chunk granularity (row-aligned layouts, 0 mod 32 row stride)
__device__ __forceinline__ int kt_off(int r, int chunk) {   // kt: 64 rows x 512B, short idx
  return r * 256 + (((chunk & 24) | ((chunk ^ r) & 7)) << 3);
}
__device__ __forceinline__ int vt_off(int r, int chunk) {   // vt: 256 rows x 128B, short idx
  return r * 64 + (((chunk ^ r) & 7) << 3);
}

// ---------------- transpose: x (B,C,N) f32 -> Xt (B,N,C) fp16 ----------------
__global__ __launch_bounds__(256) void k_transpose(const float* __restrict__ x,
                                                   unsigned short* __restrict__ Xt) {
  __shared__ float tile[64][65];
  int b = blockIdx.z, c0 = blockIdx.y * 64, n0 = blockIdx.x * 64;
  int t = threadIdx.x;
  const float* xp = x + ((size_t)b * CC + c0) * NN + n0;
#pragma unroll
  for (int p = 0; p < 4; ++p) {
    int c = p * 16 + (t >> 4);
    int j = (t & 15) * 4;
    float4 v = *(const float4*)(xp + (size_t)c * NN + j);
    tile[c][j] = v.x; tile[c][j + 1] = v.y; tile[c][j + 2] = v.z; tile[c][j + 3] = v.w;
  }
  __syncthreads();
  unsigned short* xtp = Xt + ((size_t)b * NN + n0) * CC + c0;
#pragma unroll
  for (int p = 0; p < 2; ++p) {
    int n = p * 32 + (t >> 3);
    int cb = (t & 7) * 8;
    union { unsigned short u[8]; uint4 v; } tmp;
#pragma unroll
    for (int i = 0; i < 8; ++i) tmp.u[i] = f2h(tile[cb + i][n]);
    *(uint4*)(xtp + (size_t)n * CC + cb) = tmp.v;
  }
}

// ---------------- projections ----------------
__global__ __launch_bounds__(256, 1) void k_proj(const unsigned short* __restrict__ Xt,
    const float* __restrict__ Wq, const float* __restrict__ bq,
    const float* __restrict__ Wk, const float* __restrict__ bk,
    const float* __restrict__ Wv, const float* __restrict__ bv,
    unsigned short* __restrict__ Q, unsigned short* __restrict__ K,
    unsigned short* __restrict__ V) {
  __shared__ union {
    struct { unsigned short xa[128][72]; unsigned short wb[256][72]; } s;
    unsigned short qo[128][264];
    unsigned short vo[256][136];
  } u;
  int proj = blockIdx.z;
  const float* W    = proj == 0 ? Wq : (proj == 1 ? Wk : Wv);
  const float* bias = proj == 0 ? bq : (proj == 1 ? bk : bv);
  int b = blockIdx.y, n0 = blockIdx.x * 128;
  int t = threadIdx.x, w = t >> 6, lane = t & 63, l15 = lane & 15, quad = lane >> 4;

  f32x4 z = {0.f, 0.f, 0.f, 0.f};
  f32x4 acc[2][16];
#pragma unroll
  for (int i = 0; i < 2; ++i)
#pragma unroll
    for (int j = 0; j < 16; ++j) acc[i][j] = z;

  for (int ks = 0; ks < 4; ++ks) {
    __syncthreads();
#pragma unroll
    for (int p = 0; p < 4; ++p) {
      int r = p * 32 + (t >> 3);
      *(uint4*)&u.s.xa[r][(t & 7) * 8] =
        *(const uint4*)(Xt + ((size_t)b * NN + n0 + r) * CC + ks * 64 + (t & 7) * 8);
    }
#pragma unroll
    for (int p = 0; p < 16; ++p) {
      int r = p * 16 + (t >> 4);
      float4 wv = *(const float4*)(W + (size_t)r * CC + ks * 64 + (t & 15) * 4);
      ushort4 pk;
      pk.x = f2h(wv.x); pk.y = f2h(wv.y); pk.z = f2h(wv.z); pk.w = f2h(wv.w);
      *(ushort4*)&u.s.wb[r][(t & 15) * 4] = pk;
    }
    __syncthreads();
#pragma unroll
    for (int kc = 0; kc < 2; ++kc) {
      half8 af[2];
#pragma unroll
      for (int nt = 0; nt < 2; ++nt)
        af[nt] = *(const half8*)&u.s.xa[w * 32 + nt * 16 + l15][kc * 32 + quad * 8];
#pragma unroll
      for (int ct = 0; ct < 16; ++ct) {
        half8 bf = *(const half8*)&u.s.wb[ct * 16 + l15][kc * 32 + quad * 8];
        acc[0][ct] = __builtin_amdgcn_mfma_f32_16x16x32_f16(af[0], bf, acc[0][ct], 0, 0, 0);
        acc[1][ct] = __builtin_amdgcn_mfma_f32_16x16x32_f16(af[1], bf, acc[1][ct], 0, 0, 0);
      }
    }
  }
#pragma unroll
  for (int ct = 0; ct < 16; ++ct) {
    float bv_ = bias[ct * 16 + l15];
#pragma unroll
    for (int nt = 0; nt < 2; ++nt)
#pragma unroll
      for (int r = 0; r < 4; ++r) acc[nt][ct][r] += bv_;
  }
  __syncthreads();
  if (proj < 2) {
#pragma unroll
    for (int nt = 0; nt < 2; ++nt)
#pragma unroll
      for (int ct = 0; ct < 16; ++ct)
#pragma unroll
        for (int r = 0; r < 4; ++r)
          u.qo[w * 32 + nt * 16 + quad * 4 + r][ct * 16 + l15] = f2h(acc[nt][ct][r]);
    __syncthreads();
    unsigned short* out = (proj == 0 ? Q : K) + ((size_t)b * NN + n0) * CC;
#pragma unroll
    for (int p = 0; p < 16; ++p) {
      int f = p * 4096 + t * 16;
      int n = f >> 9, ob = f & 511;
      *(uint4*)((char*)out + (size_t)n * 512 + ob) =
        *(const uint4*)((const char*)&u.qo[n][0] + ob);
    }
  } else {
#pragma unroll
    for (int nt = 0; nt < 2; ++nt)
#pragma unroll
      for (int ct = 0; ct < 16; ++ct)
#pragma unroll
        for (int r = 0; r < 4; ++r)
          u.vo[ct * 16 + l15][w * 32 + nt * 16 + quad * 4 + r] = f2h(acc[nt][ct][r]);
    __syncthreads();
    unsigned short* out = V + (size_t)b * CC * NN + n0;
#pragma unroll
    for (int p = 0; p < 16; ++p) {
      int o = p * 16 + (t >> 4);
      *(uint4*)((char*)out + (size_t)o * NN * 2 + (t & 15) * 16) =
        *(const uint4*)&u.vo[o][(t & 15) * 8];
    }
  }
}

// ---------------- flash attention (8 waves, register-prefetch pipeline) ----------------
// out[b,c,n] = sum_m softmax_m(Q[n,:].K[m,:]) * V[c,m]
__global__ __launch_bounds__(512, 2) void k_flash(const unsigned short* __restrict__ Q,
    const unsigned short* __restrict__ K, const unsigned short* __restrict__ V,
    float* __restrict__ out, float* __restrict__ opart, float* __restrict__ ml,
    int n_splits) {
  __shared__ union {
    struct {
      unsigned short kt[16384];   // 64 keys x 256 c (swizzled), 32KB
      unsigned short vt[16384];   // 256 c x 64 keys (swizzled), 32KB
      unsigned short pt[8192];    // 8 waves x 16 q x 64 keys (swizzled), 16KB
    } s;
    float od[128][132];           // epilogue half-tile: [c][q]
  } u;
  int b = blockIdx.y, q0 = blockIdx.x * 128, split = blockIdx.z;
  int nper = 64 / n_splits;
  int t = threadIdx.x, w = t >> 6, lane = t & 63, l15 = lane & 15, quad = lane >> 4;

  // Q fragments in registers (loop-invariant): A[q=l15][c=quad*8+j]
  half8 qf[8];
  const unsigned short* qrow = Q + ((size_t)b * NN + q0 + w * 16 + l15) * CC;
#pragma unroll
  for (int k = 0; k < 8; ++k) qf[k] = *(const half8*)(qrow + k * 32 + quad * 8);

  f32x4 z = {0.f, 0.f, 0.f, 0.f};
  f32x4 o_acc[16];
#pragma unroll
  for (int i = 0; i < 16; ++i) o_acc[i] = z;
  float m_i[4], lp_[4];
#pragma unroll
  for (int r = 0; r < 4; ++r) { m_i[r] = -INFINITY; lp_[r] = 0.f; }

  int it_beg = split * nper, it_end = it_beg + nper;
  uint4 kreg[4], vreg[4];

  // prologue: fetch tile it_beg to regs, write to LDS
  {
    const char* kb = (const char*)(K + ((size_t)b * NN + it_beg * 64) * CC);
    const char* vb = (const char*)(V + (size_t)b * CC * NN + it_beg * 64);
#pragma unroll
    for (int p = 0; p < 4; ++p) {
      int f = p * 8192 + t * 16;
      kreg[p] = *(const uint4*)(kb + f);
      vreg[p] = *(const uint4*)(vb + (size_t)(f >> 7) * 8192 + (f & 127));
    }
#pragma unroll
    for (int p = 0; p < 4; ++p) {
      int f = p * 8192 + t * 16;
      *(uint4*)&u.s.kt[kt_off(f >> 9, (f >> 4) & 31)] = kreg[p];
      *(uint4*)&u.s.vt[vt_off(f >> 7, (f >> 4) & 7)] = vreg[p];
    }
  }
  __syncthreads();

  for (int it = it_beg; it < it_end; ++it) {
    bool has_next = (it + 1 < it_end);
    if (has_next) {   // issue next tile's loads; latency hides behind compute
      const char* kb = (const char*)(K + ((size_t)b * NN + (it + 1) * 64) * CC);
      const char* vb = (const char*)(V + (size_t)b * CC * NN + (it + 1) * 64);
#pragma unroll
      for (int p = 0; p < 4; ++p) {
        int f = p * 8192 + t * 16;
        kreg[p] = *(const uint4*)(kb + f);
        vreg[p] = *(const uint4*)(vb + (size_t)(f >> 7) * 8192 + (f & 127));
      }
    }

    // S = Q K^T : 16 q x 64 keys per wave
    f32x4 sa[4];
#pragma unroll
    for (int j = 0; j < 4; ++j) sa[j] = z;
#pragma unroll
    for (int k = 0; k < 8; ++k) {
#pragma unroll
      for (int j = 0; j < 4; ++j) {
        half8 bf = *(const half8*)&u.s.kt[kt_off(j * 16 + l15, 4 * k + quad)];
        sa[j] = __builtin_amdgcn_mfma_f32_16x16x32_f16(qf[k], bf, sa[j], 0, 0, 0);
      }
    }
    // online softmax: max butterfly only; sum kept per-lane (reduced after loop)
    float mt[4];
#pragma unroll
    for (int r = 0; r < 4; ++r)
      mt[r] = fmaxf(fmaxf(sa[0][r], sa[1][r]), fmaxf(sa[2][r], sa[3][r]));
#pragma unroll
    for (int off = 1; off < 16; off <<= 1)
#pragma unroll
      for (int r = 0; r < 4; ++r)
        mt[r] = fmaxf(mt[r], __shfl_xor(mt[r], off, 64));
    float alpha[4];
#pragma unroll
    for (int r = 0; r < 4; ++r) {
      float mn = fmaxf(m_i[r], mt[r]);
      alpha[r] = __expf(m_i[r] - mn);
      m_i[r] = mn;
    }
#pragma unroll
    for (int r = 0; r < 4; ++r) {
      float ls = 0.f;
#pragma unroll
      for (int j = 0; j < 4; ++j) {
        float p = __expf(sa[j][r] - m_i[r]);
        sa[j][r] = p;
        ls += p;
      }
      lp_[r] = lp_[r] * alpha[r] + ls;
    }
#pragma unroll
    for (int ct = 0; ct < 16; ++ct)
#pragma unroll
      for (int r = 0; r < 4; ++r) o_acc[ct][r] *= alpha[r];
    // P (C/D layout) -> LDS -> A-operand layout (within-wave)
#pragma unroll
    for (int j = 0; j < 4; ++j)
#pragma unroll
      for (int r = 0; r < 4; ++r) {
        int row = quad * 4 + r;
        int chunk = 2 * j + (l15 >> 3);
        u.s.pt[w * 1024 + row * 64 + (((chunk ^ row) & 7) << 3) + (l15 & 7)] = f2h(sa[j][r]);
      }
    // O += P @ V^T
#pragma unroll
    for (int mc = 0; mc < 2; ++mc) {
      half8 af = *(const half8*)&u.s.pt[w * 1024 + l15 * 64 + ((((mc * 4 + quad) ^ l15) & 7) << 3)];
#pragma unroll
      for (int ct = 0; ct < 16; ++ct) {
        half8 bf = *(const half8*)&u.s.vt[vt_off(ct * 16 + l15, mc * 4 + quad)];
        o_acc[ct] = __builtin_amdgcn_mfma_f32_16x16x32_f16(af, bf, o_acc[ct], 0, 0, 0);
      }
    }

    if (has_next) {
      __syncthreads();   // all waves done reading current tile
#pragma unroll
      for (int p = 0; p < 4; ++p) {
        int f = p * 8192 + t * 16;
        *(uint4*)&u.s.kt[kt_off(f >> 9, (f >> 4) & 31)] = kreg[p];
        *(uint4*)&u.s.vt[vt_off(f >> 7, (f >> 4) & 7)] = vreg[p];
      }
      __syncthreads();   // new tile visible
    }
  }

  // final 16-lane sum reduction of l partials
#pragma unroll
  for (int off = 1; off < 16; off <<= 1)
#pragma unroll
    for (int r = 0; r < 4; ++r)
      lp_[r] += __shfl_xor(lp_[r], off, 64);

  float sc[4];
#pragma unroll
  for (int r = 0; r < 4; ++r) sc[r] = (n_splits == 1) ? 1.f / lp_[r] : 1.f;

  float* ob = (n_splits == 1 ? out : opart + (size_t)split * BB * CC * NN)
              + (size_t)b * CC * NN + q0;
#pragma unroll
  for (int half = 0; half < 2; ++half) {
    __syncthreads();
#pragma unroll
    for (int ct = half * 8; ct < half * 8 + 8; ++ct)
#pragma unroll
      for (int r = 0; r < 4; ++r)
        u.od[(ct - half * 8) * 16 + l15][w * 16 + quad * 4 + r] = o_acc[ct][r] * sc[r];
    __syncthreads();
#pragma unroll
    for (int p = 0; p < 8; ++p) {
      int cr = p * 16 + (t >> 5);
      *(float4*)(ob + (size_t)(half * 128 + cr) * NN + (t & 31) * 4) =
        *(const float4*)&u.od[cr][(t & 31) * 4];
    }
  }
  if (n_splits != 1 && l15 == 0) {
    float* mp = ml + ((size_t)(split * 2 + 0) * BB + b) * NN + q0 + w * 16 + quad * 4;
    float* lq = ml + ((size_t)(split * 2 + 1) * BB + b) * NN + q0 + w * 16 + quad * 4;
#pragma unroll
    for (int r = 0; r < 4; ++r) { mp[r] = m_i[r]; lq[r] = lp_[r]; }
  }
}

// ---------------- merge of 2 key-splits ----------------
__global__ __launch_bounds__(256) void k_merge(const float* __restrict__ opart,
    const float* __restrict__ ml, float* __restrict__ out) {
  size_t i = ((size_t)blockIdx.x * 256 + threadIdx.x) * 4;
  int n = (int)(i & (NN - 1));
  int b = (int)(i >> 20);   // i / (CC*NN)
  float4 m1 = *(const float4*)(ml + (size_t)(0 * BB + b) * NN + n);
  float4 l1 = *(const float4*)(ml + (size_t)(1 * BB + b) * NN + n);
  float4 m2 = *(const float4*)(ml + (size_t)(2 * BB + b) * NN + n);
  float4 l2 = *(const float4*)(ml + (size_t)(3 * BB + b) * NN + n);
  float4 o1 = *(const float4*)(opart + i);
  float4 o2 = *(const float4*)(opart + (size_t)BB * CC * NN + i);
  float4 o;
#define MERGE1(f) { \
    float mm = fmaxf(m1.f, m2.f); \
    float e1 = __expf(m1.f - mm), e2 = __expf(m2.f - mm); \
    o.f = (e1 * o1.f + e2 * o2.f) / (e1 * l1.f + e2 * l2.f); }
  MERGE1(x) MERGE1(y) MERGE1(z) MERGE1(w)
#undef MERGE1
  *(float4*)(out + i) = o;
}

extern "C" void kernel_launch(void* const* d_in, const int* in_sizes, int n_in,
                              void* d_out, int out_size, void* d_ws, size_t ws_size,
                              hipStream_t stream) {
  const float* x  = (const float*)d_in[0];
  const float* Wq = (const float*)d_in[1];
  const float* bq = (const float*)d_in[2];
  const float* Wk = (const float*)d_in[3];
  const float* bk = (const float*)d_in[4];
  const float* Wv = (const float*)d_in[5];
  const float* bv = (const float*)d_in[6];
  float* out = (float*)d_out;
  char* ws = (char*)d_ws;
  unsigned short* Xt = (unsigned short*)(ws);
  unsigned short* Qb = (unsigned short*)(ws + (size_t)8  * 1024 * 1024);
  unsigned short* Kb = (unsigned short*)(ws + (size_t)16 * 1024 * 1024);
  unsigned short* Vb = (unsigned short*)(ws + (size_t)24 * 1024 * 1024);
  float* Opart = (float*)(ws + (size_t)32 * 1024 * 1024);  // 2 x 16 MB
  float* Ml    = (float*)(ws + (size_t)64 * 1024 * 1024);  // 4 x 64 KB

  k_transpose<<<dim3(64, 4, 4), 256, 0, stream>>>(x, Xt);
  k_proj<<<dim3(32, 4, 3), 256, 0, stream>>>(Xt, Wq, bq, Wk, bk, Wv, bv, Qb, Kb, Vb);

  bool split2 = ws_size >= (size_t)68 * 1024 * 1024;
  if (split2) {
    k_flash<<<dim3(32, 4, 2), 512, 0, stream>>>(Qb, Kb, Vb, out, Opart, Ml, 2);
    k_merge<<<dim3(4096), 256, 0, stream>>>(Opart, Ml, out);
  } else {
    k_flash<<<dim3(32, 4, 1), 512, 0, stream>>>(Qb, Kb, Vb, out, Opart, Ml, 1);
  }
}

// Round 6
// 525.016 us; speedup vs baseline: 1.3182x; 1.0015x over previous
//
#include <hip/hip_runtime.h>
#include <math.h>

#define BB 4
#define CC 256
#define NN 4096

using half8 = __attribute__((ext_vector_type(8))) _Float16;
using f32x4 = __attribute__((ext_vector_type(4))) float;

__device__ __forceinline__ unsigned short f2h(float f) {
  _Float16 h = (_Float16)f;   // RNE
  return __builtin_bit_cast(unsigned short, h);
}

// XOR bank swizzle at 16B-chunk granularity (row-aligned layouts, 0 mod 32 row stride)
__device__ __forceinline__ int kt_off(int r, int chunk) {   // kt: 64 rows x 512B, short idx
  return r * 256 + (((chunk & 24) | ((chunk ^ r) & 7)) << 3);
}
__device__ __forceinline__ int vt_off(int r, int chunk) {   // vt: 256 rows x 128B, short idx
  return r * 64 + (((chunk ^ r) & 7) << 3);
}

// ---------------- transpose: x (B,C,N) f32 -> Xt (B,N,C) fp16 ----------------
__global__ __launch_bounds__(256) void k_transpose(const float* __restrict__ x,
                                                   unsigned short* __restrict__ Xt) {
  __shared__ float tile[64][65];
  int b = blockIdx.z, c0 = blockIdx.y * 64, n0 = blockIdx.x * 64;
  int t = threadIdx.x;
  const float* xp = x + ((size_t)b * CC + c0) * NN + n0;
#pragma unroll
  for (int p = 0; p < 4; ++p) {
    int c = p * 16 + (t >> 4);
    int j = (t & 15) * 4;
    float4 v = *(const float4*)(xp + (size_t)c * NN + j);
    tile[c][j] = v.x; tile[c][j + 1] = v.y; tile[c][j + 2] = v.z; tile[c][j + 3] = v.w;
  }
  __syncthreads();
  unsigned short* xtp = Xt + ((size_t)b * NN + n0) * CC + c0;
#pragma unroll
  for (int p = 0; p < 2; ++p) {
    int n = p * 32 + (t >> 3);
    int cb = (t & 7) * 8;
    union { unsigned short u[8]; uint4 v; } tmp;
#pragma unroll
    for (int i = 0; i < 8; ++i) tmp.u[i] = f2h(tile[cb + i][n]);
    *(uint4*)(xtp + (size_t)n * CC + cb) = tmp.v;
  }
}

// ---------------- projections ----------------
__global__ __launch_bounds__(256, 1) void k_proj(const unsigned short* __restrict__ Xt,
    const float* __restrict__ Wq, const float* __restrict__ bq,
    const float* __restrict__ Wk, const float* __restrict__ bk,
    const float* __restrict__ Wv, const float* __restrict__ bv,
    unsigned short* __restrict__ Q, unsigned short* __restrict__ K,
    unsigned short* __restrict__ V) {
  __shared__ union {
    struct { unsigned short xa[128][72]; unsigned short wb[256][72]; } s;
    unsigned short qo[128][264];
    unsigned short vo[256][136];
  } u;
  int proj = blockIdx.z;
  const float* W    = proj == 0 ? Wq : (proj == 1 ? Wk : Wv);
  const float* bias = proj == 0 ? bq : (proj == 1 ? bk : bv);
  int b = blockIdx.y, n0 = blockIdx.x * 128;
  int t = threadIdx.x, w = t >> 6, lane = t & 63, l15 = lane & 15, quad = lane >> 4;

  f32x4 z = {0.f, 0.f, 0.f, 0.f};
  f32x4 acc[2][16];
#pragma unroll
  for (int i = 0; i < 2; ++i)
#pragma unroll
    for (int j = 0; j < 16; ++j) acc[i][j] = z;

  for (int ks = 0; ks < 4; ++ks) {
    __syncthreads();
#pragma unroll
    for (int p = 0; p < 4; ++p) {
      int r = p * 32 + (t >> 3);
      *(uint4*)&u.s.xa[r][(t & 7) * 8] =
        *(const uint4*)(Xt + ((size_t)b * NN + n0 + r) * CC + ks * 64 + (t & 7) * 8);
    }
#pragma unroll
    for (int p = 0; p < 16; ++p) {
      int r = p * 16 + (t >> 4);
      float4 wv = *(const float4*)(W + (size_t)r * CC + ks * 64 + (t & 15) * 4);
      ushort4 pk;
      pk.x = f2h(wv.x); pk.y = f2h(wv.y); pk.z = f2h(wv.z); pk.w = f2h(wv.w);
      *(ushort4*)&u.s.wb[r][(t & 15) * 4] = pk;
    }
    __syncthreads();
#pragma unroll
    for (int kc = 0; kc < 2; ++kc) {
      half8 af[2];
#pragma unroll
      for (int nt = 0; nt < 2; ++nt)
        af[nt] = *(const half8*)&u.s.xa[w * 32 + nt * 16 + l15][kc * 32 + quad * 8];
#pragma unroll
      for (int ct = 0; ct < 16; ++ct) {
        half8 bf = *(const half8*)&u.s.wb[ct * 16 + l15][kc * 32 + quad * 8];
        acc[0][ct] = __builtin_amdgcn_mfma_f32_16x16x32_f16(af[0], bf, acc[0][ct], 0, 0, 0);
        acc[1][ct] = __builtin_amdgcn_mfma_f32_16x16x32_f16(af[1], bf, acc[1][ct], 0, 0, 0);
      }
    }
  }
#pragma unroll
  for (int ct = 0; ct < 16; ++ct) {
    float bv_ = bias[ct * 16 + l15];
#pragma unroll
    for (int nt = 0; nt < 2; ++nt)
#pragma unroll
      for (int r = 0; r < 4; ++r) acc[nt][ct][r] += bv_;
  }
  __syncthreads();
  if (proj < 2) {
#pragma unroll
    for (int nt = 0; nt < 2; ++nt)
#pragma unroll
      for (int ct = 0; ct < 16; ++ct)
#pragma unroll
        for (int r = 0; r < 4; ++r)
          u.qo[w * 32 + nt * 16 + quad * 4 + r][ct * 16 + l15] = f2h(acc[nt][ct][r]);
    __syncthreads();
    unsigned short* out = (proj == 0 ? Q : K) + ((size_t)b * NN + n0) * CC;
#pragma unroll
    for (int p = 0; p < 16; ++p) {
      int f = p * 4096 + t * 16;
      int n = f >> 9, ob = f & 511;
      *(uint4*)((char*)out + (size_t)n * 512 + ob) =
        *(const uint4*)((const char*)&u.qo[n][0] + ob);
    }
  } else {
#pragma unroll
    for (int nt = 0; nt < 2; ++nt)
#pragma unroll
      for (int ct = 0; ct < 16; ++ct)
#pragma unroll
        for (int r = 0; r < 4; ++r)
          u.vo[ct * 16 + l15][w * 32 + nt * 16 + quad * 4 + r] = f2h(acc[nt][ct][r]);
    __syncthreads();
    unsigned short* out = V + (size_t)b * CC * NN + n0;
#pragma unroll
    for (int p = 0; p < 16; ++p) {
      int o = p * 16 + (t >> 4);
      *(uint4*)((char*)out + (size_t)o * NN * 2 + (t & 15) * 16) =
        *(const uint4*)&u.vo[o][(t & 15) * 8];
    }
  }
}

// ---------------- flash attention (8 waves, register-prefetch pipeline) ----------------
// out[b,c,n] = sum_m softmax_m(Q[n,:].K[m,:]) * V[c,m]
// __launch_bounds__(512, 1): min-waves/SIMD=1 -> VGPR cap 256. The kernel's live
// set is ~200 VGPRs; capping at 128 (512,2) spilled o_acc to scratch (506 MB of
// HBM write traffic measured in round 5). 1 block/CU x 8 waves = the occupancy.
__global__ __launch_bounds__(512, 1) void k_flash(const unsigned short* __restrict__ Q,
    const unsigned short* __restrict__ K, const unsigned short* __restrict__ V,
    float* __restrict__ out, float* __restrict__ opart, float* __restrict__ ml,
    int n_splits) {
  __shared__ union {
    struct {
      unsigned short kt[16384];   // 64 keys x 256 c (swizzled), 32KB
      unsigned short vt[16384];   // 256 c x 64 keys (swizzled), 32KB
      unsigned short pt[8192];    // 8 waves x 16 q x 64 keys (swizzled), 16KB
    } s;
    float od[128][132];           // epilogue half-tile: [c][q]
  } u;
  int b = blockIdx.y, q0 = blockIdx.x * 128, split = blockIdx.z;
  int nper = 64 / n_splits;
  int t = threadIdx.x, w = t >> 6, lane = t & 63, l15 = lane & 15, quad = lane >> 4;

  // Q fragments in registers (loop-invariant): A[q=l15][c=quad*8+j]
  half8 qf[8];
  const unsigned short* qrow = Q + ((size_t)b * NN + q0 + w * 16 + l15) * CC;
#pragma unroll
  for (int k = 0; k < 8; ++k) qf[k] = *(const half8*)(qrow + k * 32 + quad * 8);

  f32x4 z = {0.f, 0.f, 0.f, 0.f};
  f32x4 o_acc[16];
#pragma unroll
  for (int i = 0; i < 16; ++i) o_acc[i] = z;
  float m_i[4], lp_[4];
#pragma unroll
  for (int r = 0; r < 4; ++r) { m_i[r] = -INFINITY; lp_[r] = 0.f; }

  int it_beg = split * nper, it_end = it_beg + nper;
  uint4 kreg[4], vreg[4];

  // prologue: fetch tile it_beg to regs, write to LDS
  {
    const char* kb = (const char*)(K + ((size_t)b * NN + it_beg * 64) * CC);
    const char* vb = (const char*)(V + (size_t)b * CC * NN + it_beg * 64);
#pragma unroll
    for (int p = 0; p < 4; ++p) {
      int f = p * 8192 + t * 16;
      kreg[p] = *(const uint4*)(kb + f);
      vreg[p] = *(const uint4*)(vb + (size_t)(f >> 7) * 8192 + (f & 127));
    }
#pragma unroll
    for (int p = 0; p < 4; ++p) {
      int f = p * 8192 + t * 16;
      *(uint4*)&u.s.kt[kt_off(f >> 9, (f >> 4) & 31)] = kreg[p];
      *(uint4*)&u.s.vt[vt_off(f >> 7, (f >> 4) & 7)] = vreg[p];
    }
  }
  __syncthreads();

  for (int it = it_beg; it < it_end; ++it) {
    bool has_next = (it + 1 < it_end);
    if (has_next) {   // issue next tile's loads; latency hides behind compute
      const char* kb = (const char*)(K + ((size_t)b * NN + (it + 1) * 64) * CC);
      const char* vb = (const char*)(V + (size_t)b * CC * NN + (it + 1) * 64);
#pragma unroll
      for (int p = 0; p < 4; ++p) {
        int f = p * 8192 + t * 16;
        kreg[p] = *(const uint4*)(kb + f);
        vreg[p] = *(const uint4*)(vb + (size_t)(f >> 7) * 8192 + (f & 127));
      }
    }

    // S = Q K^T : 16 q x 64 keys per wave
    f32x4 sa[4];
#pragma unroll
    for (int j = 0; j < 4; ++j) sa[j] = z;
#pragma unroll
    for (int k = 0; k < 8; ++k) {
#pragma unroll
      for (int j = 0; j < 4; ++j) {
        half8 bf = *(const half8*)&u.s.kt[kt_off(j * 16 + l15, 4 * k + quad)];
        sa[j] = __builtin_amdgcn_mfma_f32_16x16x32_f16(qf[k], bf, sa[j], 0, 0, 0);
      }
    }
    // online softmax: max butterfly only; sum kept per-lane (reduced after loop)
    float mt[4];
#pragma unroll
    for (int r = 0; r < 4; ++r)
      mt[r] = fmaxf(fmaxf(sa[0][r], sa[1][r]), fmaxf(sa[2][r], sa[3][r]));
#pragma unroll
    for (int off = 1; off < 16; off <<= 1)
#pragma unroll
      for (int r = 0; r < 4; ++r)
        mt[r] = fmaxf(mt[r], __shfl_xor(mt[r], off, 64));
    float alpha[4];
#pragma unroll
    for (int r = 0; r < 4; ++r) {
      float mn = fmaxf(m_i[r], mt[r]);
      alpha[r] = __expf(m_i[r] - mn);
      m_i[r] = mn;
    }
#pragma unroll
    for (int r = 0; r < 4; ++r) {
      float ls = 0.f;
#pragma unroll
      for (int j = 0; j < 4; ++j) {
        float p = __expf(sa[j][r] - m_i[r]);
        sa[j][r] = p;
        ls += p;
      }
      lp_[r] = lp_[r] * alpha[r] + ls;
    }
#pragma unroll
    for (int ct = 0; ct < 16; ++ct)
#pragma unroll
      for (int r = 0; r < 4; ++r) o_acc[ct][r] *= alpha[r];
    // P (C/D layout) -> LDS -> A-operand layout (within-wave)
#pragma unroll
    for (int j = 0; j < 4; ++j)
#pragma unroll
      for (int r = 0; r < 4; ++r) {
        int row = quad * 4 + r;
        int chunk = 2 * j + (l15 >> 3);
        u.s.pt[w * 1024 + row * 64 + (((chunk ^ row) & 7) << 3) + (l15 & 7)] = f2h(sa[j][r]);
      }
    // O += P @ V^T
#pragma unroll
    for (int mc = 0; mc < 2; ++mc) {
      half8 af = *(const half8*)&u.s.pt[w * 1024 + l15 * 64 + ((((mc * 4 + quad) ^ l15) & 7) << 3)];
#pragma unroll
      for (int ct = 0; ct < 16; ++ct) {
        half8 bf = *(const half8*)&u.s.vt[vt_off(ct * 16 + l15, mc * 4 + quad)];
        o_acc[ct] = __builtin_amdgcn_mfma_f32_16x16x32_f16(af, bf, o_acc[ct], 0, 0, 0);
      }
    }

    if (has_next) {
      __syncthreads();   // all waves done reading current tile
#pragma unroll
      for (int p = 0; p < 4; ++p) {
        int f = p * 8192 + t * 16;
        *(uint4*)&u.s.kt[kt_off(f >> 9, (f >> 4) & 31)] = kreg[p];
        *(uint4*)&u.s.vt[vt_off(f >> 7, (f >> 4) & 7)] = vreg[p];
      }
      __syncthreads();   // new tile visible
    }
  }

  // final 16-lane sum reduction of l partials
#pragma unroll
  for (int off = 1; off < 16; off <<= 1)
#pragma unroll
    for (int r = 0; r < 4; ++r)
      lp_[r] += __shfl_xor(lp_[r], off, 64);

  float sc[4];
#pragma unroll
  for (int r = 0; r < 4; ++r) sc[r] = (n_splits == 1) ? 1.f / lp_[r] : 1.f;

  float* ob = (n_splits == 1 ? out : opart + (size_t)split * BB * CC * NN)
              + (size_t)b * CC * NN + q0;
#pragma unroll
  for (int half = 0; half < 2; ++half) {
    __syncthreads();
#pragma unroll
    for (int ct = half * 8; ct < half * 8 + 8; ++ct)
#pragma unroll
      for (int r = 0; r < 4; ++r)
        u.od[(ct - half * 8) * 16 + l15][w * 16 + quad * 4 + r] = o_acc[ct][r] * sc[r];
    __syncthreads();
#pragma unroll
    for (int p = 0; p < 8; ++p) {
      int cr = p * 16 + (t >> 5);
      *(float4*)(ob + (size_t)(half * 128 + cr) * NN + (t & 31) * 4) =
        *(const float4*)&u.od[cr][(t & 31) * 4];
    }
  }
  if (n_splits != 1 && l15 == 0) {
    float* mp = ml + ((size_t)(split * 2 + 0) * BB + b) * NN + q0 + w * 16 + quad * 4;
    float* lq = ml + ((size_t)(split * 2 + 1) * BB + b) * NN + q0 + w * 16 + quad * 4;
#pragma unroll
    for (int r = 0; r < 4; ++r) { mp[r] = m_i[r]; lq[r] = lp_[r]; }
  }
}

// ---------------- merge of 2 key-splits ----------------
__global__ __launch_bounds__(256) void k_merge(const float* __restrict__ opart,
    const float* __restrict__ ml, float* __restrict__ out) {
  size_t i = ((size_t)blockIdx.x * 256 + threadIdx.x) * 4;
  int n = (int)(i & (NN - 1));
  int b = (int)(i >> 20);   // i / (CC*NN)
  float4 m1 = *(const float4*)(ml + (size_t)(0 * BB + b) * NN + n);
  float4 l1 = *(const float4*)(ml + (size_t)(1 * BB + b) * NN + n);
  float4 m2 = *(const float4*)(ml + (size_t)(2 * BB + b) * NN + n);
  float4 l2 = *(const float4*)(ml + (size_t)(3 * BB + b) * NN + n);
  float4 o1 = *(const float4*)(opart + i);
  float4 o2 = *(const float4*)(opart + (size_t)BB * CC * NN + i);
  float4 o;
#define MERGE1(f) { \
    float mm = fmaxf(m1.f, m2.f); \
    float e1 = __expf(m1.f - mm), e2 = __expf(m2.f - mm); \
    o.f = (e1 * o1.f + e2 * o2.f) / (e1 * l1.f + e2 * l2.f); }
  MERGE1(x) MERGE1(y) MERGE1(z) MERGE1(w)
#undef MERGE1
  *(float4*)(out + i) = o;
}

extern "C" void kernel_launch(void* const* d_in, const int* in_sizes, int n_in,
                              void* d_out, int out_size, void* d_ws, size_t ws_size,
                              hipStream_t stream) {
  const float* x  = (const float*)d_in[0];
  const float* Wq = (const float*)d_in[1];
  const float* bq = (const float*)d_in[2];
  const float* Wk = (const float*)d_in[3];
  const float* bk = (const float*)d_in[4];
  const float* Wv = (const float*)d_in[5];
  const float* bv = (const float*)d_in[6];
  float* out = (float*)d_out;
  char* ws = (char*)d_ws;
  unsigned short* Xt = (unsigned short*)(ws);
  unsigned short* Qb = (unsigned short*)(ws + (size_t)8  * 1024 * 1024);
  unsigned short* Kb = (unsigned short*)(ws + (size_t)16 * 1024 * 1024);
  unsigned short* Vb = (unsigned short*)(ws + (size_t)24 * 1024 * 1024);
  float* Opart = (float*)(ws + (size_t)32 * 1024 * 1024);  // 2 x 16 MB
  float* Ml    = (float*)(ws + (size_t)64 * 1024 * 1024);  // 4 x 64 KB

  k_transpose<<<dim3(64, 4, 4), 256, 0, stream>>>(x, Xt);
  k_proj<<<dim3(32, 4, 3), 256, 0, stream>>>(Xt, Wq, bq, Wk, bk, Wv, bv, Qb, Kb, Vb);

  bool split2 = ws_size >= (size_t)68 * 1024 * 1024;
  if (split2) {
    k_flash<<<dim3(32, 4, 2), 512, 0, stream>>>(Qb, Kb, Vb, out, Opart, Ml, 2);
    k_merge<<<dim3(4096), 256, 0, stream>>>(Opart, Ml, out);
  } else {
    k_flash<<<dim3(32, 4, 1), 512, 0, stream>>>(Qb, Kb, Vb, out, Opart, Ml, 1);
  }
}